// Round 20
// baseline (366.300 us; speedup 1.0000x reference)
//
#include <hip/hip_runtime.h>
#include <hip/hip_bf16.h>
#include <stdint.h>

typedef __attribute__((ext_vector_type(8))) short s16x8;
typedef __attribute__((ext_vector_type(4))) float f32x4;

#define D_MODEL 768
#define N_HEADS 6
#define HD 128
#define RANK 192
#define TT 256
#define NROW 32768         // B*T
#define NK 12              // 768 / 64 K-tiles
#define QSCL 0.08838834764831845f
#define PSTRIDE 25165824   // elements per packed tensor: 768*256*128

__device__ inline short f2bf(float f) {
  union { float f; unsigned u; } x; x.f = f;
  unsigned r = x.u + 0x7fffu + ((x.u >> 16) & 1u);
  return (short)(r >> 16);
}
__device__ inline float bf2f(short v) {
  union { unsigned u; float f; } x; x.u = ((unsigned)(unsigned short)v) << 16;
  return x.f;
}
__device__ inline void gload_lds16(const void* g, void* lds) {
  __builtin_amdgcn_global_load_lds(
      (const __attribute__((address_space(1))) unsigned int*)g,
      (__attribute__((address_space(3))) unsigned int*)lds, 16, 0, 0);
}

#define BAR()    asm volatile("s_barrier" ::: "memory")
#define LGKM0()  asm volatile("s_waitcnt lgkmcnt(0)" ::: "memory")
#define WAITVM4() asm volatile("s_waitcnt vmcnt(4)" ::: "memory")
#define WAITVM0() asm volatile("s_waitcnt vmcnt(0)" ::: "memory")
#define SCHB()   __builtin_amdgcn_sched_barrier(0)

// ---------------- RoPE tables: cos/sin [256][64] fp32 ----------------
__global__ void k_tables(float* __restrict__ cosT, float* __restrict__ sinT) {
  int tid = blockIdx.x * 256 + threadIdx.x;   // 16384 total
  int t = tid >> 6, i = tid & 63;
  float inv = powf(10000.0f, -(float)i / 64.0f);
  float ang = (float)t * inv;
  cosT[tid] = cosf(ang);
  sinT[tid] = sinf(ang);
}

// ---------------- cast x fp32 -> bf16 ----------------
__global__ void k_castx(const float* __restrict__ x, short* __restrict__ xb) {
  int t = blockIdx.x * 256 + threadIdx.x;     // NROW*768/8 threads
  const float4* xp = (const float4*)x;
  float4 a = xp[t * 2], b = xp[t * 2 + 1];
  s16x8 o;
  o[0] = f2bf(a.x); o[1] = f2bf(a.y); o[2] = f2bf(a.z); o[3] = f2bf(a.w);
  o[4] = f2bf(b.x); o[5] = f2bf(b.y); o[6] = f2bf(b.z); o[7] = f2bf(b.w);
  *(s16x8*)(xb + (size_t)t * 8) = o;
}

// ---------------- combined low-rank weights, transposed, float4 loads ----------------
__global__ void k_makew(const float* __restrict__ qA, const float* __restrict__ qB,
                        const float* __restrict__ kA, const float* __restrict__ kB,
                        const float* __restrict__ vA, const float* __restrict__ vB,
                        short* __restrict__ WT) {
  int g = blockIdx.x * 256 + threadIdx.x;
  int n4 = g % 576, kkb = g / 576;            // kkb in [0,192)
  int part = n4 / 192, nnb = (n4 % 192) * 4;
  const float* A = (part == 0) ? qA : (part == 1) ? kA : vA;
  const float* Bm = (part == 0) ? qB : (part == 1) ? kB : vB;
  float acc[4][4] = {};
  for (int r0 = 0; r0 < RANK; r0 += 4) {
    float4 a4[4], b4[4];
#pragma unroll
    for (int q = 0; q < 4; ++q)
      a4[q] = *(const float4*)&A[(kkb + q * 192) * RANK + r0];
#pragma unroll
    for (int i = 0; i < 4; ++i)
      b4[i] = *(const float4*)&Bm[(r0 + i) * 768 + nnb];
#pragma unroll
    for (int q = 0; q < 4; ++q) {
      const float* aq = (const float*)&a4[q];
#pragma unroll
      for (int i = 0; i < 4; ++i) {
        const float* bi = (const float*)&b4[i];
#pragma unroll
        for (int jn = 0; jn < 4; ++jn)
          acc[q][jn] += aq[i] * bi[jn];
      }
    }
  }
#pragma unroll
  for (int q = 0; q < 4; ++q)
#pragma unroll
    for (int jn = 0; jn < 4; ++jn)
      WT[(size_t)(part * 768 + nnb + jn) * 768 + kkb + q * 192] = f2bf(acc[q][jn]);
}

// ---------------- o_w transposed -> WT rows [2304,3072) ----------------
__global__ void k_wot(const float* __restrict__ ow, short* __restrict__ WT) {
  int g = blockIdx.x * 256 + threadIdx.x;     // 768*768 total
  int n = g % 768, kk = g / 768;
  WT[(size_t)(2304 + n) * 768 + kk] = f2bf(ow[(size_t)kk * 768 + n]);
}

// =====================================================================
// 256x256 8-phase GEMM (T2+T3+T4+T5), K=768, BK=64, 8 waves (2x4).
// XCD-chunked block mapping. MODE 0: fp32 out [row][ldc].
// MODE 2: bf16 out packed qkv — part p at Cv + p*PSTRIDE, [(b*6+h)][t][d].
// =====================================================================
__device__ inline s16x8 rdfrag(const short* hbase, int rowbyte, int ksl4x, int swz) {
  return *(const s16x8*)((const char*)hbase + rowbyte + (((ksl4x) ^ (swz)) << 4));
}

template <int MODE>
__global__ __launch_bounds__(512, 2) void k_gemm8(const short* __restrict__ A,
                                                  const short* __restrict__ Bt,
                                                  void* __restrict__ Cv, int ldc) {
  extern __shared__ short lds[];
  const int tid = threadIdx.x;
  const int wid = tid >> 6, lane = tid & 63;
  const int l15 = lane & 15, l4 = lane >> 4;
  const int wr = wid >> 2, wc = wid & 3;
  const int swz = l15 & 7;
  const int bid = blockIdx.y * 128 + blockIdx.x;
  const int nper = gridDim.y;
  const int xcd = bid & 7, loc = bid >> 3;
  const int mq = loc / nper;
  const int mt = xcd * 16 + mq;
  const int nt = loc - mq * nper;
  const long mbase = (long)mt * 256;
  const long nbase = (long)nt * 256;

  const int hb0 = wid * 2048 + lane * 16;
  const int hb1 = hb0 + 1024;
  const int r0 = hb0 >> 7, c0 = ((hb0 >> 4) & 7) ^ (r0 & 7);
  const int r1 = hb1 >> 7, c1 = ((hb1 >> 4) & 7) ^ (r1 & 7);
  const int off0 = r0 * 768 + c0 * 8;
  const int off1 = r1 * 768 + c1 * 8;

#define STAGE(G, rowoff, kt, ldsS) do {                                        \
    gload_lds16((G) + (size_t)(rowoff) * 768 + (kt) * 64 + off0,               \
                (char*)(ldsS) + wid * 2048);                                   \
    gload_lds16((G) + (size_t)(rowoff) * 768 + (kt) * 64 + off1,               \
                (char*)(ldsS) + wid * 2048 + 1024);                            \
  } while (0)

#define LDSA(buf, half) (lds + ((buf) * 2 + (half)) * 8192)
#define LDSB(buf, half) (lds + 32768 + ((buf) * 2 + (half)) * 8192)

  f32x4 acc[8][4] = {};

  STAGE(A,  mbase,       0, LDSA(0, 0));
  STAGE(Bt, nbase,       0, LDSB(0, 0));
  STAGE(A,  mbase + 128, 0, LDSA(0, 1));
  STAGE(Bt, nbase + 128, 0, LDSB(0, 1));
  STAGE(A,  mbase,       1, LDSA(1, 0));
  STAGE(Bt, nbase,       1, LDSB(1, 0));
  WAITVM4();
  BAR();

  s16x8 a03[4][2], a47[4][2], b01[2][2], b23[2][2];

#pragma unroll
  for (int kt = 0; kt < NK; ++kt) {
    const int buf = kt & 1, nbuf = buf ^ 1;
    const short* Ab = LDSA(buf, wr);
    const short* Bb = LDSB(buf, (wc >> 1));
    const int browbase = (wc & 1) * 64 * 128;

    // P0
#pragma unroll
    for (int mf = 0; mf < 4; ++mf)
#pragma unroll
      for (int ks = 0; ks < 2; ++ks)
        a03[mf][ks] = rdfrag(Ab, (mf * 16 + l15) * 128, ks * 4 + l4, swz);
#pragma unroll
    for (int nf = 0; nf < 2; ++nf)
#pragma unroll
      for (int ks = 0; ks < 2; ++ks)
        b01[nf][ks] = rdfrag(Bb, browbase + (nf * 16 + l15) * 128, ks * 4 + l4, swz);
    if (kt + 1 < NK) STAGE(A, mbase + 128, kt + 1, LDSA(nbuf, 1));
    BAR();
    LGKM0();
    __builtin_amdgcn_s_setprio(1);
#pragma unroll
    for (int mf = 0; mf < 4; ++mf)
#pragma unroll
      for (int nf = 0; nf < 2; ++nf)
#pragma unroll
        for (int ks = 0; ks < 2; ++ks)
          acc[mf][nf] = __builtin_amdgcn_mfma_f32_16x16x32_bf16(a03[mf][ks], b01[nf][ks], acc[mf][nf], 0, 0, 0);
    __builtin_amdgcn_s_setprio(0);
    BAR();

    // P1
#pragma unroll
    for (int mf = 0; mf < 4; ++mf)
#pragma unroll
      for (int ks = 0; ks < 2; ++ks)
        a47[mf][ks] = rdfrag(Ab, ((mf + 4) * 16 + l15) * 128, ks * 4 + l4, swz);
    if (kt + 1 < NK) STAGE(Bt, nbase + 128, kt + 1, LDSB(nbuf, 1));
    BAR();
    LGKM0();
    __builtin_amdgcn_s_setprio(1);
#pragma unroll
    for (int mf = 0; mf < 4; ++mf)
#pragma unroll
      for (int nf = 0; nf < 2; ++nf)
#pragma unroll
        for (int ks = 0; ks < 2; ++ks)
          acc[mf + 4][nf] = __builtin_amdgcn_mfma_f32_16x16x32_bf16(a47[mf][ks], b01[nf][ks], acc[mf + 4][nf], 0, 0, 0);
    __builtin_amdgcn_s_setprio(0);
    BAR();

    // P2
#pragma unroll
    for (int nf = 0; nf < 2; ++nf)
#pragma unroll
      for (int ks = 0; ks < 2; ++ks)
        b23[nf][ks] = rdfrag(Bb, browbase + ((nf + 2) * 16 + l15) * 128, ks * 4 + l4, swz);
    if (kt + 2 < NK) STAGE(A, mbase, kt + 2, LDSA(buf, 0));
    BAR();
    LGKM0();
    __builtin_amdgcn_s_setprio(1);
#pragma unroll
    for (int mf = 0; mf < 4; ++mf)
#pragma unroll
      for (int nf = 0; nf < 2; ++nf)
#pragma unroll
        for (int ks = 0; ks < 2; ++ks)
          acc[mf][nf + 2] = __builtin_amdgcn_mfma_f32_16x16x32_bf16(a03[mf][ks], b23[nf][ks], acc[mf][nf + 2], 0, 0, 0);
    __builtin_amdgcn_s_setprio(0);
    BAR();

    // P3
    if (kt + 2 < NK) STAGE(Bt, nbase, kt + 2, LDSB(buf, 0));
    BAR();
    __builtin_amdgcn_s_setprio(1);
#pragma unroll
    for (int mf = 0; mf < 4; ++mf)
#pragma unroll
      for (int nf = 0; nf < 2; ++nf)
#pragma unroll
        for (int ks = 0; ks < 2; ++ks)
          acc[mf + 4][nf + 2] = __builtin_amdgcn_mfma_f32_16x16x32_bf16(a47[mf][ks], b23[nf][ks], acc[mf + 4][nf + 2], 0, 0, 0);
    __builtin_amdgcn_s_setprio(0);
    if (kt < NK - 1) {
      if (kt + 2 < NK) WAITVM4(); else WAITVM0();
      BAR();
    }
  }
#undef STAGE

#pragma unroll
  for (int mf = 0; mf < 8; ++mf)
#pragma unroll
    for (int nf = 0; nf < 4; ++nf) {
      const int col = (int)(nbase + wc * 64 + nf * 16 + l15);
      const int part = col / 768;
      const int wi = col - part * 768;
      const int hh = wi >> 7, dd = wi & 127;
#pragma unroll
      for (int r = 0; r < 4; ++r) {
        long row = mbase + wr * 128 + mf * 16 + l4 * 4 + r;
        if (MODE == 0) {
          ((float*)Cv)[row * ldc + col] = acc[mf][nf][r];
        } else {
          size_t idx = (size_t)part * PSTRIDE +
                       (((size_t)(row >> 8) * 6 + hh) * 256 + (row & 255)) * 128 + dd;
          ((short*)Cv)[idx] = f2bf(acc[mf][nf][r]);
        }
      }
    }
}

// ---------------- RoPE on k only (packed layout, contiguous) ----------------
__global__ void k_ropek(short* __restrict__ kp, const float* __restrict__ cosT,
                        const float* __restrict__ sinT) {
  int tid = blockIdx.x * 256 + threadIdx.x;   // 768*256*8 total
  int bh = tid >> 11, rem = tid & 2047;
  int t = rem >> 3, i8 = (rem & 7) * 8;
  size_t base = ((size_t)bh * 256 + t) * 128 + i8;
  s16x8 a = *(const s16x8*)(kp + base);
  s16x8 b = *(const s16x8*)(kp + base + 64);
  const float4* cp = (const float4*)(cosT + t * 64 + i8);
  const float4* sp = (const float4*)(sinT + t * 64 + i8);
  float4 c04 = cp[0], c14 = cp[1], s04 = sp[0], s14 = sp[1];
  float cs[8] = {c04.x, c04.y, c04.z, c04.w, c14.x, c14.y, c14.z, c14.w};
  float sn[8] = {s04.x, s04.y, s04.z, s04.w, s14.x, s14.y, s14.z, s14.w};
  s16x8 na, nb;
#pragma unroll
  for (int j = 0; j < 8; ++j) {
    float av = bf2f(a[j]), bv = bf2f(b[j]);
    na[j] = f2bf(av * cs[j] - bv * sn[j]);
    nb[j] = f2bf(bv * cs[j] + av * sn[j]);
  }
  *(s16x8*)(kp + base) = na;
  *(s16x8*)(kp + base + 64) = nb;
}

// ---------------- flash attention: barrier-free main loop, 160KB LDS ----------------
// Prologue stages ALL 4 K tiles (gload_lds) and ALL 4 V tiles (reg->swizzled
// Vt), then ONE vmcnt(0)+lgkmcnt(0)+barrier. Main loop per wave j=0..jmax:
// QK^T -> softmax -> P write -> lgkmcnt(0, own-wave) -> PV. No barriers, no
// vmcnt; causal waves exit early. All layouts identical to proven kernel.
__global__ __launch_bounds__(512) void k_attn(const short* __restrict__ qp,
                                              const short* __restrict__ kp,
                                              const short* __restrict__ vp,
                                              short* __restrict__ attout,
                                              const float* __restrict__ cosT,
                                              const float* __restrict__ sinT) {
  extern __shared__ short smem[];
  // K[j] at smem + j*8192 (64KB); Vt[j] at smem + 32768 + j*8192 (64KB);
  // Pls per-wave at smem + 65536 + wid*2048 (32KB). Total 160KB.
  const int tid = threadIdx.x;
  const int wid = tid >> 6, lane = tid & 63;
  const int l15 = lane & 15, l4 = lane >> 4;
  short* PlsW = smem + 65536 + wid * 2048;
  const int bh = blockIdx.x;            // b*N_HEADS + h
  const int b = bh / N_HEADS, h = bh % N_HEADS;
  const long row0 = (long)b * TT;
  const size_t pbase = (size_t)bh * 256 * 128;
  const int d0 = wid * 16;

  // --- load raw Q fragments, rope + scale in-register ---
  s16x8 qf[2][4];
#pragma unroll
  for (int mi = 0; mi < 2; ++mi)
#pragma unroll
    for (int kc = 0; kc < 4; ++kc) {
      int t = wid * 32 + mi * 16 + l15;
      qf[mi][kc] = *(const s16x8*)(qp + pbase + (size_t)t * 128 + kc * 32 + l4 * 8);
    }
#pragma unroll
  for (int mi = 0; mi < 2; ++mi) {
    int t = wid * 32 + mi * 16 + l15;
#pragma unroll
    for (int kc = 0; kc < 2; ++kc) {
      const float4* cp = (const float4*)(cosT + t * 64 + kc * 32 + l4 * 8);
      const float4* sp = (const float4*)(sinT + t * 64 + kc * 32 + l4 * 8);
      float4 c04 = cp[0], c14 = cp[1], s04 = sp[0], s14 = sp[1];
      float cs[8] = {c04.x, c04.y, c04.z, c04.w, c14.x, c14.y, c14.z, c14.w};
      float sn[8] = {s04.x, s04.y, s04.z, s04.w, s14.x, s14.y, s14.z, s14.w};
#pragma unroll
      for (int jj = 0; jj < 8; ++jj) {
        float av = bf2f(qf[mi][kc][jj]);
        float bv = bf2f(qf[mi][kc + 2][jj]);
        qf[mi][kc][jj]     = f2bf((av * cs[jj] - bv * sn[jj]) * QSCL);
        qf[mi][kc + 2][jj] = f2bf((bv * cs[jj] + av * sn[jj]) * QSCL);
      }
    }
  }

#define STAGEK(j_) do {                                                         \
    int bb0_ = wid * 2048 + lane * 16;                                          \
    int r0_ = bb0_ >> 8; int sc0_ = ((bb0_ >> 4) & 15) ^ (r0_ & 7);             \
    gload_lds16(kp + pbase + (size_t)((j_) * 64 + r0_) * 128 + sc0_ * 8,        \
                (char*)(smem + (j_) * 8192) + wid * 2048);                      \
    int bb1_ = bb0_ + 1024;                                                     \
    int r1_ = bb1_ >> 8; int sc1_ = ((bb1_ >> 4) & 15) ^ (r1_ & 7);             \
    gload_lds16(kp + pbase + (size_t)((j_) * 64 + r1_) * 128 + sc1_ * 8,        \
                (char*)(smem + (j_) * 8192) + wid * 2048 + 1024);               \
  } while (0)

#define LOADV(j_, va, vb) do {                                                  \
    const short* vsrc_ = vp + pbase + (size_t)((j_) * 64 + lane) * 128 + d0;    \
    va = *(const s16x8*)vsrc_;                                                  \
    vb = *(const s16x8*)(vsrc_ + 8);                                            \
  } while (0)

  float mst[2][4], lst[2][4];
  f32x4 oacc[2][8];
#pragma unroll
  for (int mi = 0; mi < 2; ++mi)
#pragma unroll
    for (int r = 0; r < 4; ++r) { mst[mi][r] = -1e30f; lst[mi][r] = 0.f; }
#pragma unroll
  for (int mi = 0; mi < 2; ++mi)
#pragma unroll
    for (int nd = 0; nd < 8; ++nd) oacc[mi][nd] = {0.f, 0.f, 0.f, 0.f};

  const int jmax = (wid * 32 + 31) / 64;

  // prologue: issue all K stages + V loads
  s16x8 vr[4][2];
  STAGEK(0); STAGEK(1); STAGEK(2); STAGEK(3);
  LOADV(0, vr[0][0], vr[0][1]);
  LOADV(1, vr[1][0], vr[1][1]);
  LOADV(2, vr[2][0], vr[2][1]);
  LOADV(3, vr[3][0], vr[3][1]);
  WAITVM0();
  SCHB();
  // transpose-write all 4 V tiles into swizzled Vt buffers
#pragma unroll
  for (int jt = 0; jt < 4; ++jt) {
    char* Vtj = (char*)(smem + 32768 + jt * 8192);
#pragma unroll
    for (int e = 0; e < 8; ++e)
      *(short*)(Vtj + (d0 + e) * 128 + (((lane >> 3) ^ e) << 4) + (lane & 7) * 2) = vr[jt][0][e];
#pragma unroll
    for (int e = 0; e < 8; ++e)
      *(short*)(Vtj + (d0 + 8 + e) * 128 + (((lane >> 3) ^ e) << 4) + (lane & 7) * 2) = vr[jt][1][e];
  }
  LGKM0();
  BAR();                                   // single block-wide sync

  for (int j = 0; j <= jmax; ++j) {
    const short* Kb  = smem + j * 8192;
    const char*  Vtj = (const char*)(smem + 32768 + j * 8192);
    // --- S = Q K^T ---
    f32x4 sacc[2][4] = {};
#pragma unroll
    for (int kc = 0; kc < 4; ++kc) {
      s16x8 kf[4];
#pragma unroll
      for (int ni = 0; ni < 4; ++ni)
        kf[ni] = *(const s16x8*)((const char*)Kb + (ni * 16 + l15) * 256 +
                                 (((kc * 4 + l4) ^ (l15 & 7)) << 4));
#pragma unroll
      for (int mi = 0; mi < 2; ++mi)
#pragma unroll
        for (int ni = 0; ni < 4; ++ni)
          sacc[mi][ni] = __builtin_amdgcn_mfma_f32_16x16x32_bf16(qf[mi][kc], kf[ni], sacc[mi][ni], 0, 0, 0);
    }
    // --- causal mask + online softmax ---
#pragma unroll
    for (int mi = 0; mi < 2; ++mi) {
#pragma unroll
      for (int r = 0; r < 4; ++r) {
        int qr = wid * 32 + mi * 16 + l4 * 4 + r;
        float rm = -1e30f;
#pragma unroll
        for (int ni = 0; ni < 4; ++ni) {
          int kvc = j * 64 + ni * 16 + l15;
          if (kvc > qr) sacc[mi][ni][r] = -1e30f;
          rm = fmaxf(rm, sacc[mi][ni][r]);
        }
#pragma unroll
        for (int d2 = 1; d2 < 16; d2 <<= 1)
          rm = fmaxf(rm, __shfl_xor(rm, d2, 64));
        float mold = mst[mi][r];
        float mnew = fmaxf(mold, rm);
        float alpha = __expf(mold - mnew);
        mst[mi][r] = mnew;
        float rs = 0.f;
#pragma unroll
        for (int ni = 0; ni < 4; ++ni) {
          float p = __expf(sacc[mi][ni][r] - mnew);
          sacc[mi][ni][r] = p;
          rs += p;
        }
#pragma unroll
        for (int d2 = 1; d2 < 16; d2 <<= 1)
          rs += __shfl_xor(rs, d2, 64);
        lst[mi][r] = lst[mi][r] * alpha + rs;
#pragma unroll
        for (int nd = 0; nd < 8; ++nd)
          oacc[mi][nd][r] *= alpha;
      }
    }
    // --- P -> bf16 into swizzled per-wave Pls ---
#pragma unroll
    for (int mi = 0; mi < 2; ++mi)
#pragma unroll
      for (int ni = 0; ni < 4; ++ni)
#pragma unroll
        for (int r = 0; r < 4; ++r) {
          int prow = mi * 16 + l4 * 4 + r;
          int pcp = (ni * 2 + (l15 >> 3)) ^ (prow & 7);
          *(short*)((char*)PlsW + prow * 128 + (pcp << 4) + (l15 & 7) * 2) =
              f2bf(sacc[mi][ni][r]);
        }
    LGKM0();                               // own-wave P writes complete
    SCHB();
    // --- O += P V ---
#pragma unroll
    for (int kc2 = 0; kc2 < 2; ++kc2) {
      s16x8 pa[2];
#pragma unroll
      for (int mi = 0; mi < 2; ++mi)
        pa[mi] = *(const s16x8*)((const char*)PlsW + (mi * 16 + l15) * 128 +
                                 (((kc2 * 4 + l4) ^ (l15 & 7)) << 4));
#pragma unroll
      for (int nd = 0; nd < 8; ++nd) {
        s16x8 vf = *(const s16x8*)(Vtj + (nd * 16 + l15) * 128 +
                                   (((kc2 * 4 + l4) ^ (l15 & 7)) << 4));
#pragma unroll
        for (int mi = 0; mi < 2; ++mi)
          oacc[mi][nd] = __builtin_amdgcn_mfma_f32_16x16x32_bf16(pa[mi], vf, oacc[mi][nd], 0, 0, 0);
      }
    }
  }
#undef STAGEK
#undef LOADV
#pragma unroll
  for (int mi = 0; mi < 2; ++mi)
#pragma unroll
    for (int nd = 0; nd < 8; ++nd)
#pragma unroll
      for (int r = 0; r < 4; ++r) {
        long row = row0 + wid * 32 + mi * 16 + l4 * 4 + r;
        int col = h * HD + nd * 16 + l15;
        attout[row * D_MODEL + col] = f2bf(oacc[mi][nd][r] / lst[mi][r]);
      }
}

extern "C" void kernel_launch(void* const* d_in, const int* in_sizes, int n_in,
                              void* d_out, int out_size, void* d_ws, size_t ws_size,
                              hipStream_t stream) {
  const float* x  = (const float*)d_in[0];
  const float* qA = (const float*)d_in[1];
  const float* qB = (const float*)d_in[2];
  const float* kA = (const float*)d_in[3];
  const float* kB = (const float*)d_in[4];
  const float* vA = (const float*)d_in[5];
  const float* vB = (const float*)d_in[6];
  const float* ow = (const float*)d_in[7];

  char* ws = (char*)d_ws;
  short* qkvp  = (short*)ws;                          // 3 packed tensors, 48MB each
  short* qp    = qkvp;
  short* kp    = qkvp + (size_t)PSTRIDE;
  short* vp    = qkvp + (size_t)2 * PSTRIDE;
  short* xb    = (short*)(ws + 150994944);            // [32768][768] bf16; reused as attout
  short* WT    = (short*)(ws + 201326592);            // [3072][768]  bf16
  float* cosT  = (float*)(ws + 206045184);            // [256][64] fp32
  float* sinT  = (float*)(ws + 206110720);            // [256][64] fp32
  short* attout = xb;

  hipFuncSetAttribute((const void*)k_gemm8<2>,
                      hipFuncAttributeMaxDynamicSharedMemorySize, 131072);
  hipFuncSetAttribute((const void*)k_gemm8<0>,
                      hipFuncAttributeMaxDynamicSharedMemorySize, 131072);
  hipFuncSetAttribute((const void*)k_attn,
                      hipFuncAttributeMaxDynamicSharedMemorySize, 163840);

  k_tables<<<64, 256, 0, stream>>>(cosT, sinT);
  k_castx<<<12288, 256, 0, stream>>>(x, xb);
  k_makew<<<432, 256, 0, stream>>>(qA, qB, kA, kB, vA, vB, WT);
  k_wot<<<2304, 256, 0, stream>>>(ow, WT);
  // qkv = xb @ [Wq|Wk|Wv], written packed [(b*6+h)][t][d] per part
  k_gemm8<2><<<dim3(128, 9), 512, 131072, stream>>>(xb, WT, (void*)qkvp, 0);
  // rope k in place (packed, contiguous)
  k_ropek<<<6144, 256, 0, stream>>>(kp, cosT, sinT);
  // attention -> attout (aliases xb), barrier-free main loop, 160KB LDS
  k_attn<<<768, 512, 163840, stream>>>(qp, kp, vp, attout, cosT, sinT);
  // final projection -> d_out fp32  (M=32768, N=768, K=768)
  k_gemm8<0><<<dim3(128, 3), 512, 131072, stream>>>(attout, WT + (size_t)2304 * 768, d_out, 768);
}

// Round 21
// 354.430 us; speedup vs baseline: 1.0335x; 1.0335x over previous
//
#include <hip/hip_runtime.h>
#include <hip/hip_bf16.h>
#include <stdint.h>

typedef __attribute__((ext_vector_type(8))) short s16x8;
typedef __attribute__((ext_vector_type(4))) float f32x4;

#define D_MODEL 768
#define N_HEADS 6
#define HD 128
#define RANK 192
#define TT 256
#define NROW 32768         // B*T
#define NK 12              // 768 / 64 K-tiles
#define QSCL 0.08838834764831845f
#define PSTRIDE 25165824   // elements per packed tensor: 768*256*128

__device__ inline short f2bf(float f) {
  union { float f; unsigned u; } x; x.f = f;
  unsigned r = x.u + 0x7fffu + ((x.u >> 16) & 1u);
  return (short)(r >> 16);
}
__device__ inline float bf2f(short v) {
  union { unsigned u; float f; } x; x.u = ((unsigned)(unsigned short)v) << 16;
  return x.f;
}
__device__ inline void gload_lds16(const void* g, void* lds) {
  __builtin_amdgcn_global_load_lds(
      (const __attribute__((address_space(1))) unsigned int*)g,
      (__attribute__((address_space(3))) unsigned int*)lds, 16, 0, 0);
}

#define BAR()    asm volatile("s_barrier" ::: "memory")
#define LGKM0()  asm volatile("s_waitcnt lgkmcnt(0)" ::: "memory")
#define WAITVM4() asm volatile("s_waitcnt vmcnt(4)" ::: "memory")
#define WAITVM0() asm volatile("s_waitcnt vmcnt(0)" ::: "memory")

// ---------------- RoPE tables: cos/sin [256][64] fp32 ----------------
__global__ void k_tables(float* __restrict__ cosT, float* __restrict__ sinT) {
  int tid = blockIdx.x * 256 + threadIdx.x;   // 16384 total
  int t = tid >> 6, i = tid & 63;
  float inv = powf(10000.0f, -(float)i / 64.0f);
  float ang = (float)t * inv;
  cosT[tid] = cosf(ang);
  sinT[tid] = sinf(ang);
}

// ---------------- cast x fp32 -> bf16 ----------------
__global__ void k_castx(const float* __restrict__ x, short* __restrict__ xb) {
  int t = blockIdx.x * 256 + threadIdx.x;     // NROW*768/8 threads
  const float4* xp = (const float4*)x;
  float4 a = xp[t * 2], b = xp[t * 2 + 1];
  s16x8 o;
  o[0] = f2bf(a.x); o[1] = f2bf(a.y); o[2] = f2bf(a.z); o[3] = f2bf(a.w);
  o[4] = f2bf(b.x); o[5] = f2bf(b.y); o[6] = f2bf(b.z); o[7] = f2bf(b.w);
  *(s16x8*)(xb + (size_t)t * 8) = o;
}

// ---------------- combined low-rank weights, transposed, float4 loads ----------------
__global__ void k_makew(const float* __restrict__ qA, const float* __restrict__ qB,
                        const float* __restrict__ kA, const float* __restrict__ kB,
                        const float* __restrict__ vA, const float* __restrict__ vB,
                        short* __restrict__ WT) {
  int g = blockIdx.x * 256 + threadIdx.x;
  int n4 = g % 576, kkb = g / 576;            // kkb in [0,192)
  int part = n4 / 192, nnb = (n4 % 192) * 4;
  const float* A = (part == 0) ? qA : (part == 1) ? kA : vA;
  const float* Bm = (part == 0) ? qB : (part == 1) ? kB : vB;
  float acc[4][4] = {};
  for (int r0 = 0; r0 < RANK; r0 += 4) {
    float4 a4[4], b4[4];
#pragma unroll
    for (int q = 0; q < 4; ++q)
      a4[q] = *(const float4*)&A[(kkb + q * 192) * RANK + r0];
#pragma unroll
    for (int i = 0; i < 4; ++i)
      b4[i] = *(const float4*)&Bm[(r0 + i) * 768 + nnb];
#pragma unroll
    for (int q = 0; q < 4; ++q) {
      const float* aq = (const float*)&a4[q];
#pragma unroll
      for (int i = 0; i < 4; ++i) {
        const float* bi = (const float*)&b4[i];
#pragma unroll
        for (int jn = 0; jn < 4; ++jn)
          acc[q][jn] += aq[i] * bi[jn];
      }
    }
  }
#pragma unroll
  for (int q = 0; q < 4; ++q)
#pragma unroll
    for (int jn = 0; jn < 4; ++jn)
      WT[(size_t)(part * 768 + nnb + jn) * 768 + kkb + q * 192] = f2bf(acc[q][jn]);
}

// ---------------- o_w transposed -> WT rows [2304,3072) ----------------
__global__ void k_wot(const float* __restrict__ ow, short* __restrict__ WT) {
  int g = blockIdx.x * 256 + threadIdx.x;     // 768*768 total
  int n = g % 768, kk = g / 768;
  WT[(size_t)(2304 + n) * 768 + kk] = f2bf(ow[(size_t)kk * 768 + n]);
}

// =====================================================================
// 256x256 8-phase GEMM (T2+T3+T4+T5), K=768, BK=64, 8 waves (2x4).
// XCD-chunked block mapping. MODE 0: fp32 out [row][ldc].
// MODE 2: bf16 out packed qkv — part p at Cv + p*PSTRIDE, [(b*6+h)][t][d].
// =====================================================================
__device__ inline s16x8 rdfrag(const short* hbase, int rowbyte, int ksl4x, int swz) {
  return *(const s16x8*)((const char*)hbase + rowbyte + (((ksl4x) ^ (swz)) << 4));
}

template <int MODE>
__global__ __launch_bounds__(512, 2) void k_gemm8(const short* __restrict__ A,
                                                  const short* __restrict__ Bt,
                                                  void* __restrict__ Cv, int ldc) {
  extern __shared__ short lds[];
  const int tid = threadIdx.x;
  const int wid = tid >> 6, lane = tid & 63;
  const int l15 = lane & 15, l4 = lane >> 4;
  const int wr = wid >> 2, wc = wid & 3;
  const int swz = l15 & 7;
  const int bid = blockIdx.y * 128 + blockIdx.x;
  const int nper = gridDim.y;
  const int xcd = bid & 7, loc = bid >> 3;
  const int mq = loc / nper;
  const int mt = xcd * 16 + mq;
  const int nt = loc - mq * nper;
  const long mbase = (long)mt * 256;
  const long nbase = (long)nt * 256;

  const int hb0 = wid * 2048 + lane * 16;
  const int hb1 = hb0 + 1024;
  const int r0 = hb0 >> 7, c0 = ((hb0 >> 4) & 7) ^ (r0 & 7);
  const int r1 = hb1 >> 7, c1 = ((hb1 >> 4) & 7) ^ (r1 & 7);
  const int off0 = r0 * 768 + c0 * 8;
  const int off1 = r1 * 768 + c1 * 8;

#define STAGE(G, rowoff, kt, ldsS) do {                                        \
    gload_lds16((G) + (size_t)(rowoff) * 768 + (kt) * 64 + off0,               \
                (char*)(ldsS) + wid * 2048);                                   \
    gload_lds16((G) + (size_t)(rowoff) * 768 + (kt) * 64 + off1,               \
                (char*)(ldsS) + wid * 2048 + 1024);                            \
  } while (0)

#define LDSA(buf, half) (lds + ((buf) * 2 + (half)) * 8192)
#define LDSB(buf, half) (lds + 32768 + ((buf) * 2 + (half)) * 8192)

  f32x4 acc[8][4] = {};

  STAGE(A,  mbase,       0, LDSA(0, 0));
  STAGE(Bt, nbase,       0, LDSB(0, 0));
  STAGE(A,  mbase + 128, 0, LDSA(0, 1));
  STAGE(Bt, nbase + 128, 0, LDSB(0, 1));
  STAGE(A,  mbase,       1, LDSA(1, 0));
  STAGE(Bt, nbase,       1, LDSB(1, 0));
  WAITVM4();
  BAR();

  s16x8 a03[4][2], a47[4][2], b01[2][2], b23[2][2];

#pragma unroll
  for (int kt = 0; kt < NK; ++kt) {
    const int buf = kt & 1, nbuf = buf ^ 1;
    const short* Ab = LDSA(buf, wr);
    const short* Bb = LDSB(buf, (wc >> 1));
    const int browbase = (wc & 1) * 64 * 128;

    // P0
#pragma unroll
    for (int mf = 0; mf < 4; ++mf)
#pragma unroll
      for (int ks = 0; ks < 2; ++ks)
        a03[mf][ks] = rdfrag(Ab, (mf * 16 + l15) * 128, ks * 4 + l4, swz);
#pragma unroll
    for (int nf = 0; nf < 2; ++nf)
#pragma unroll
      for (int ks = 0; ks < 2; ++ks)
        b01[nf][ks] = rdfrag(Bb, browbase + (nf * 16 + l15) * 128, ks * 4 + l4, swz);
    if (kt + 1 < NK) STAGE(A, mbase + 128, kt + 1, LDSA(nbuf, 1));
    BAR();
    LGKM0();
    __builtin_amdgcn_s_setprio(1);
#pragma unroll
    for (int mf = 0; mf < 4; ++mf)
#pragma unroll
      for (int nf = 0; nf < 2; ++nf)
#pragma unroll
        for (int ks = 0; ks < 2; ++ks)
          acc[mf][nf] = __builtin_amdgcn_mfma_f32_16x16x32_bf16(a03[mf][ks], b01[nf][ks], acc[mf][nf], 0, 0, 0);
    __builtin_amdgcn_s_setprio(0);
    BAR();

    // P1
#pragma unroll
    for (int mf = 0; mf < 4; ++mf)
#pragma unroll
      for (int ks = 0; ks < 2; ++ks)
        a47[mf][ks] = rdfrag(Ab, ((mf + 4) * 16 + l15) * 128, ks * 4 + l4, swz);
    if (kt + 1 < NK) STAGE(Bt, nbase + 128, kt + 1, LDSB(nbuf, 1));
    BAR();
    LGKM0();
    __builtin_amdgcn_s_setprio(1);
#pragma unroll
    for (int mf = 0; mf < 4; ++mf)
#pragma unroll
      for (int nf = 0; nf < 2; ++nf)
#pragma unroll
        for (int ks = 0; ks < 2; ++ks)
          acc[mf + 4][nf] = __builtin_amdgcn_mfma_f32_16x16x32_bf16(a47[mf][ks], b01[nf][ks], acc[mf + 4][nf], 0, 0, 0);
    __builtin_amdgcn_s_setprio(0);
    BAR();

    // P2
#pragma unroll
    for (int nf = 0; nf < 2; ++nf)
#pragma unroll
      for (int ks = 0; ks < 2; ++ks)
        b23[nf][ks] = rdfrag(Bb, browbase + ((nf + 2) * 16 + l15) * 128, ks * 4 + l4, swz);
    if (kt + 2 < NK) STAGE(A, mbase, kt + 2, LDSA(buf, 0));
    BAR();
    LGKM0();
    __builtin_amdgcn_s_setprio(1);
#pragma unroll
    for (int mf = 0; mf < 4; ++mf)
#pragma unroll
      for (int nf = 0; nf < 2; ++nf)
#pragma unroll
        for (int ks = 0; ks < 2; ++ks)
          acc[mf][nf + 2] = __builtin_amdgcn_mfma_f32_16x16x32_bf16(a03[mf][ks], b23[nf][ks], acc[mf][nf + 2], 0, 0, 0);
    __builtin_amdgcn_s_setprio(0);
    BAR();

    // P3
    if (kt + 2 < NK) STAGE(Bt, nbase, kt + 2, LDSB(buf, 0));
    BAR();
    __builtin_amdgcn_s_setprio(1);
#pragma unroll
    for (int mf = 0; mf < 4; ++mf)
#pragma unroll
      for (int nf = 0; nf < 2; ++nf)
#pragma unroll
        for (int ks = 0; ks < 2; ++ks)
          acc[mf + 4][nf + 2] = __builtin_amdgcn_mfma_f32_16x16x32_bf16(a47[mf][ks], b23[nf][ks], acc[mf + 4][nf + 2], 0, 0, 0);
    __builtin_amdgcn_s_setprio(0);
    if (kt < NK - 1) {
      if (kt + 2 < NK) WAITVM4(); else WAITVM0();
      BAR();
    }
  }
#undef STAGE

#pragma unroll
  for (int mf = 0; mf < 8; ++mf)
#pragma unroll
    for (int nf = 0; nf < 4; ++nf) {
      const int col = (int)(nbase + wc * 64 + nf * 16 + l15);
      const int part = col / 768;
      const int wi = col - part * 768;
      const int hh = wi >> 7, dd = wi & 127;
#pragma unroll
      for (int r = 0; r < 4; ++r) {
        long row = mbase + wr * 128 + mf * 16 + l4 * 4 + r;
        if (MODE == 0) {
          ((float*)Cv)[row * ldc + col] = acc[mf][nf][r];
        } else {
          // packed: part tensor, [(b*6+h)][t][d]
          size_t idx = (size_t)part * PSTRIDE +
                       (((size_t)(row >> 8) * 6 + hh) * 256 + (row & 255)) * 128 + dd;
          ((short*)Cv)[idx] = f2bf(acc[mf][nf][r]);
        }
      }
    }
}

// ---------------- RoPE on k only (packed layout, contiguous) ----------------
__global__ void k_ropek(short* __restrict__ kp, const float* __restrict__ cosT,
                        const float* __restrict__ sinT) {
  int tid = blockIdx.x * 256 + threadIdx.x;   // 768*256*8 total
  int bh = tid >> 11, rem = tid & 2047;
  int t = rem >> 3, i8 = (rem & 7) * 8;
  size_t base = ((size_t)bh * 256 + t) * 128 + i8;
  s16x8 a = *(const s16x8*)(kp + base);
  s16x8 b = *(const s16x8*)(kp + base + 64);
  const float4* cp = (const float4*)(cosT + t * 64 + i8);
  const float4* sp = (const float4*)(sinT + t * 64 + i8);
  float4 c04 = cp[0], c14 = cp[1], s04 = sp[0], s14 = sp[1];
  float cs[8] = {c04.x, c04.y, c04.z, c04.w, c14.x, c14.y, c14.z, c14.w};
  float sn[8] = {s04.x, s04.y, s04.z, s04.w, s14.x, s14.y, s14.z, s14.w};
  s16x8 na, nb;
#pragma unroll
  for (int j = 0; j < 8; ++j) {
    float av = bf2f(a[j]), bv = bf2f(b[j]);
    na[j] = f2bf(av * cs[j] - bv * sn[j]);
    nb[j] = f2bf(bv * cs[j] + av * sn[j]);
  }
  *(s16x8*)(kp + base) = na;
  *(s16x8*)(kp + base + 64) = nb;
}

// ---------------- flash attention (R4 structure, packed q/k/v) ----------------
// LDS (dynamic 80KB): Kls[2][64*128] | Vt[128*64] | Pls[8][32*64], XOR-swizzled.
__global__ __launch_bounds__(512) void k_attn(const short* __restrict__ qp,
                                              const short* __restrict__ kp,
                                              const short* __restrict__ vp,
                                              short* __restrict__ attout,
                                              const float* __restrict__ cosT,
                                              const float* __restrict__ sinT) {
  extern __shared__ short smem[];
  short* Kls0 = smem;
  short* Kls1 = smem + 8192;
  short* Vt   = smem + 16384;
  const int tid = threadIdx.x;
  const int wid = tid >> 6, lane = tid & 63;
  const int l15 = lane & 15, l4 = lane >> 4;
  short* PlsW = smem + 24576 + wid * 2048;
  const int bh = blockIdx.x;                // b*N_HEADS + h
  const int b = bh / N_HEADS, h = bh % N_HEADS;
  const long row0 = (long)b * TT;
  const size_t pbase = (size_t)bh * 256 * 128;
  const int d0 = wid * 16;

  // --- load raw Q fragments, rope + scale in-register ---
  s16x8 qf[2][4];
#pragma unroll
  for (int mi = 0; mi < 2; ++mi)
#pragma unroll
    for (int kc = 0; kc < 4; ++kc) {
      int t = wid * 32 + mi * 16 + l15;
      qf[mi][kc] = *(const s16x8*)(qp + pbase + (size_t)t * 128 + kc * 32 + l4 * 8);
    }
#pragma unroll
  for (int mi = 0; mi < 2; ++mi) {
    int t = wid * 32 + mi * 16 + l15;
#pragma unroll
    for (int kc = 0; kc < 2; ++kc) {
      const float4* cp = (const float4*)(cosT + t * 64 + kc * 32 + l4 * 8);
      const float4* sp = (const float4*)(sinT + t * 64 + kc * 32 + l4 * 8);
      float4 c04 = cp[0], c14 = cp[1], s04 = sp[0], s14 = sp[1];
      float cs[8] = {c04.x, c04.y, c04.z, c04.w, c14.x, c14.y, c14.z, c14.w};
      float sn[8] = {s04.x, s04.y, s04.z, s04.w, s14.x, s14.y, s14.z, s14.w};
#pragma unroll
      for (int jj = 0; jj < 8; ++jj) {
        float av = bf2f(qf[mi][kc][jj]);
        float bv = bf2f(qf[mi][kc + 2][jj]);
        qf[mi][kc][jj]     = f2bf((av * cs[jj] - bv * sn[jj]) * QSCL);
        qf[mi][kc + 2][jj] = f2bf((bv * cs[jj] + av * sn[jj]) * QSCL);
      }
    }
  }

#define STAGEK(j_, Kd) do {                                                     \
    int bb0_ = wid * 2048 + lane * 16;                                          \
    int r0_ = bb0_ >> 8; int sc0_ = ((bb0_ >> 4) & 15) ^ (r0_ & 7);             \
    gload_lds16(kp + pbase + (size_t)((j_) * 64 + r0_) * 128 + sc0_ * 8,        \
                (char*)(Kd) + wid * 2048);                                      \
    int bb1_ = bb0_ + 1024;                                                     \
    int r1_ = bb1_ >> 8; int sc1_ = ((bb1_ >> 4) & 15) ^ (r1_ & 7);             \
    gload_lds16(kp + pbase + (size_t)((j_) * 64 + r1_) * 128 + sc1_ * 8,        \
                (char*)(Kd) + wid * 2048 + 1024);                               \
  } while (0)

#define LOADV(j_, va, vb) do {                                                  \
    const short* vsrc_ = vp + pbase + (size_t)((j_) * 64 + lane) * 128 + d0;    \
    va = *(const s16x8*)vsrc_;                                                  \
    vb = *(const s16x8*)(vsrc_ + 8);                                            \
  } while (0)

  float mst[2][4], lst[2][4];
  f32x4 oacc[2][8];
#pragma unroll
  for (int mi = 0; mi < 2; ++mi)
#pragma unroll
    for (int r = 0; r < 4; ++r) { mst[mi][r] = -1e30f; lst[mi][r] = 0.f; }
#pragma unroll
  for (int mi = 0; mi < 2; ++mi)
#pragma unroll
    for (int nd = 0; nd < 8; ++nd) oacc[mi][nd] = {0.f, 0.f, 0.f, 0.f};

  const int jmax = (wid * 32 + 31) / 64;

  // prologue: stage tile 0
  STAGEK(0, Kls0);
  s16x8 vr[2][2];
  LOADV(0, vr[0][0], vr[0][1]);

#pragma unroll
  for (int j = 0; j < 4; ++j) {
    const int buf = j & 1;
    const short* Kb = buf ? Kls1 : Kls0;
    short* Kn = buf ? Kls0 : Kls1;
    // prefetch next tile (K -> LDS, V -> regs)
    if (j < 3) {
      STAGEK(j + 1, Kn);
      LOADV(j + 1, vr[buf ^ 1][0], vr[buf ^ 1][1]);
    }
    if (j < 3) WAITVM4(); else WAITVM0();
    __builtin_amdgcn_sched_barrier(0);
    BAR();
    // --- transpose-write V(j) into swizzled Vt ---
#pragma unroll
    for (int e = 0; e < 8; ++e)
      *(short*)((char*)Vt + (d0 + e) * 128 + (((lane >> 3) ^ e) << 4) + (lane & 7) * 2) = vr[buf][0][e];
#pragma unroll
    for (int e = 0; e < 8; ++e)
      *(short*)((char*)Vt + (d0 + 8 + e) * 128 + (((lane >> 3) ^ e) << 4) + (lane & 7) * 2) = vr[buf][1][e];

    if (j <= jmax) {
      // --- S = Q K^T ---
      f32x4 sacc[2][4] = {};
#pragma unroll
      for (int kc = 0; kc < 4; ++kc) {
        s16x8 kf[4];
#pragma unroll
        for (int ni = 0; ni < 4; ++ni)
          kf[ni] = *(const s16x8*)((const char*)Kb + (ni * 16 + l15) * 256 +
                                   (((kc * 4 + l4) ^ (l15 & 7)) << 4));
#pragma unroll
        for (int mi = 0; mi < 2; ++mi)
#pragma unroll
          for (int ni = 0; ni < 4; ++ni)
            sacc[mi][ni] = __builtin_amdgcn_mfma_f32_16x16x32_bf16(qf[mi][kc], kf[ni], sacc[mi][ni], 0, 0, 0);
      }
      // --- causal mask + online softmax ---
#pragma unroll
      for (int mi = 0; mi < 2; ++mi) {
#pragma unroll
        for (int r = 0; r < 4; ++r) {
          int qr = wid * 32 + mi * 16 + l4 * 4 + r;
          float rm = -1e30f;
#pragma unroll
          for (int ni = 0; ni < 4; ++ni) {
            int kvc = j * 64 + ni * 16 + l15;
            if (kvc > qr) sacc[mi][ni][r] = -1e30f;
            rm = fmaxf(rm, sacc[mi][ni][r]);
          }
#pragma unroll
          for (int d2 = 1; d2 < 16; d2 <<= 1)
            rm = fmaxf(rm, __shfl_xor(rm, d2, 64));
          float mold = mst[mi][r];
          float mnew = fmaxf(mold, rm);
          float alpha = __expf(mold - mnew);
          mst[mi][r] = mnew;
          float rs = 0.f;
#pragma unroll
          for (int ni = 0; ni < 4; ++ni) {
            float p = __expf(sacc[mi][ni][r] - mnew);
            sacc[mi][ni][r] = p;
            rs += p;
          }
#pragma unroll
          for (int d2 = 1; d2 < 16; d2 <<= 1)
            rs += __shfl_xor(rs, d2, 64);
          lst[mi][r] = lst[mi][r] * alpha + rs;
#pragma unroll
          for (int nd = 0; nd < 8; ++nd)
            oacc[mi][nd][r] *= alpha;
        }
      }
      // --- P -> bf16 into swizzled per-wave Pls ---
#pragma unroll
      for (int mi = 0; mi < 2; ++mi)
#pragma unroll
        for (int ni = 0; ni < 4; ++ni)
#pragma unroll
          for (int r = 0; r < 4; ++r) {
            int prow = mi * 16 + l4 * 4 + r;
            int pcp = (ni * 2 + (l15 >> 3)) ^ (prow & 7);
            *(short*)((char*)PlsW + prow * 128 + (pcp << 4) + (l15 & 7) * 2) =
                f2bf(sacc[mi][ni][r]);
          }
    }
    LGKM0();
    BAR();
    __builtin_amdgcn_sched_barrier(0);
    if (j <= jmax) {
      // --- O += P V ---
#pragma unroll
      for (int kc2 = 0; kc2 < 2; ++kc2) {
        s16x8 pa[2];
#pragma unroll
        for (int mi = 0; mi < 2; ++mi)
          pa[mi] = *(const s16x8*)((const char*)PlsW + (mi * 16 + l15) * 128 +
                                   (((kc2 * 4 + l4) ^ (l15 & 7)) << 4));
#pragma unroll
        for (int nd = 0; nd < 8; ++nd) {
          s16x8 vf = *(const s16x8*)((const char*)Vt + (nd * 16 + l15) * 128 +
                                     (((kc2 * 4 + l4) ^ (l15 & 7)) << 4));
#pragma unroll
          for (int mi = 0; mi < 2; ++mi)
            oacc[mi][nd] = __builtin_amdgcn_mfma_f32_16x16x32_bf16(pa[mi], vf, oacc[mi][nd], 0, 0, 0);
        }
      }
    }
  }
#undef STAGEK
#undef LOADV
#pragma unroll
  for (int mi = 0; mi < 2; ++mi)
#pragma unroll
    for (int nd = 0; nd < 8; ++nd)
#pragma unroll
      for (int r = 0; r < 4; ++r) {
        long row = row0 + wid * 32 + mi * 16 + l4 * 4 + r;
        int col = h * HD + nd * 16 + l15;
        attout[row * D_MODEL + col] = f2bf(oacc[mi][nd][r] / lst[mi][r]);
      }
}

extern "C" void kernel_launch(void* const* d_in, const int* in_sizes, int n_in,
                              void* d_out, int out_size, void* d_ws, size_t ws_size,
                              hipStream_t stream) {
  const float* x  = (const float*)d_in[0];
  const float* qA = (const float*)d_in[1];
  const float* qB = (const float*)d_in[2];
  const float* kA = (const float*)d_in[3];
  const float* kB = (const float*)d_in[4];
  const float* vA = (const float*)d_in[5];
  const float* vB = (const float*)d_in[6];
  const float* ow = (const float*)d_in[7];

  char* ws = (char*)d_ws;
  short* qkvp  = (short*)ws;                          // 3 packed tensors, 48MB each
  short* qp    = qkvp;
  short* kp    = qkvp + (size_t)PSTRIDE;
  short* vp    = qkvp + (size_t)2 * PSTRIDE;
  short* xb    = (short*)(ws + 150994944);            // [32768][768] bf16, reused as attout
  short* WT    = (short*)(ws + 201326592);            // [3072][768]  bf16
  float* cosT  = (float*)(ws + 206045184);            // [256][64] fp32
  float* sinT  = (float*)(ws + 206110720);            // [256][64] fp32
  short* attout = xb;

  hipFuncSetAttribute((const void*)k_gemm8<2>,
                      hipFuncAttributeMaxDynamicSharedMemorySize, 131072);
  hipFuncSetAttribute((const void*)k_gemm8<0>,
                      hipFuncAttributeMaxDynamicSharedMemorySize, 131072);
  hipFuncSetAttribute((const void*)k_attn,
                      hipFuncAttributeMaxDynamicSharedMemorySize, 81920);

  k_tables<<<64, 256, 0, stream>>>(cosT, sinT);
  k_castx<<<12288, 256, 0, stream>>>(x, xb);
  k_makew<<<432, 256, 0, stream>>>(qA, qB, kA, kB, vA, vB, WT);
  k_wot<<<2304, 256, 0, stream>>>(ow, WT);
  // qkv = xb @ [Wq|Wk|Wv], written packed [(b*6+h)][t][d] per part
  k_gemm8<2><<<dim3(128, 9), 512, 131072, stream>>>(xb, WT, (void*)qkvp, 0);
  // rope k in place (packed, contiguous)
  k_ropek<<<6144, 256, 0, stream>>>(kp, cosT, sinT);
  // attention -> attout (aliases xb)
  k_attn<<<768, 512, 81920, stream>>>(qp, kp, vp, attout, cosT, sinT);
  // final projection -> d_out fp32  (M=32768, N=768, K=768)
  k_gemm8<0><<<dim3(128, 3), 512, 131072, stream>>>(attout, WT + (size_t)2304 * 768, d_out, 768);
}

// Round 22
// 341.773 us; speedup vs baseline: 1.0718x; 1.0370x over previous
//
#include <hip/hip_runtime.h>
#include <hip/hip_bf16.h>
#include <stdint.h>

typedef __attribute__((ext_vector_type(8))) short s16x8;
typedef __attribute__((ext_vector_type(4))) float f32x4;

#define D_MODEL 768
#define N_HEADS 6
#define HD 128
#define RANK 192
#define TT 256
#define NROW 32768         // B*T
#define NK 12              // 768 / 64 K-tiles
#define QSCL 0.08838834764831845f
#define PSTRIDE 25165824   // elements per packed tensor: 768*256*128

__device__ inline short f2bf(float f) {
  union { float f; unsigned u; } x; x.f = f;
  unsigned r = x.u + 0x7fffu + ((x.u >> 16) & 1u);
  return (short)(r >> 16);
}
__device__ inline float bf2f(short v) {
  union { unsigned u; float f; } x; x.u = ((unsigned)(unsigned short)v) << 16;
  return x.f;
}
__device__ inline void gload_lds16(const void* g, void* lds) {
  __builtin_amdgcn_global_load_lds(
      (const __attribute__((address_space(1))) unsigned int*)g,
      (__attribute__((address_space(3))) unsigned int*)lds, 16, 0, 0);
}

// 16-lane reductions via DPP row_ror (VALU pipe; avoids ds_swizzle LDS ops)
__device__ inline float red16_max(float v) {
  int x;
  x = __builtin_amdgcn_update_dpp(0, __float_as_int(v), 0x121, 0xf, 0xf, true);
  v = fmaxf(v, __int_as_float(x));
  x = __builtin_amdgcn_update_dpp(0, __float_as_int(v), 0x122, 0xf, 0xf, true);
  v = fmaxf(v, __int_as_float(x));
  x = __builtin_amdgcn_update_dpp(0, __float_as_int(v), 0x124, 0xf, 0xf, true);
  v = fmaxf(v, __int_as_float(x));
  x = __builtin_amdgcn_update_dpp(0, __float_as_int(v), 0x128, 0xf, 0xf, true);
  v = fmaxf(v, __int_as_float(x));
  return v;
}
__device__ inline float red16_sum(float v) {
  int x;
  x = __builtin_amdgcn_update_dpp(0, __float_as_int(v), 0x121, 0xf, 0xf, true);
  v += __int_as_float(x);
  x = __builtin_amdgcn_update_dpp(0, __float_as_int(v), 0x122, 0xf, 0xf, true);
  v += __int_as_float(x);
  x = __builtin_amdgcn_update_dpp(0, __float_as_int(v), 0x124, 0xf, 0xf, true);
  v += __int_as_float(x);
  x = __builtin_amdgcn_update_dpp(0, __float_as_int(v), 0x128, 0xf, 0xf, true);
  v += __int_as_float(x);
  return v;
}

#define BAR()    asm volatile("s_barrier" ::: "memory")
#define LGKM0()  asm volatile("s_waitcnt lgkmcnt(0)" ::: "memory")
#define WAITVM4() asm volatile("s_waitcnt vmcnt(4)" ::: "memory")
#define WAITVM0() asm volatile("s_waitcnt vmcnt(0)" ::: "memory")

// ---------------- RoPE tables: cos/sin [256][64] fp32 ----------------
__global__ void k_tables(float* __restrict__ cosT, float* __restrict__ sinT) {
  int tid = blockIdx.x * 256 + threadIdx.x;   // 16384 total
  int t = tid >> 6, i = tid & 63;
  float inv = powf(10000.0f, -(float)i / 64.0f);
  float ang = (float)t * inv;
  cosT[tid] = cosf(ang);
  sinT[tid] = sinf(ang);
}

// ---------------- cast x fp32 -> bf16 ----------------
__global__ void k_castx(const float* __restrict__ x, short* __restrict__ xb) {
  int t = blockIdx.x * 256 + threadIdx.x;     // NROW*768/8 threads
  const float4* xp = (const float4*)x;
  float4 a = xp[t * 2], b = xp[t * 2 + 1];
  s16x8 o;
  o[0] = f2bf(a.x); o[1] = f2bf(a.y); o[2] = f2bf(a.z); o[3] = f2bf(a.w);
  o[4] = f2bf(b.x); o[5] = f2bf(b.y); o[6] = f2bf(b.z); o[7] = f2bf(b.w);
  *(s16x8*)(xb + (size_t)t * 8) = o;
}

// ---------------- combined low-rank weights, transposed, float4 loads ----------------
__global__ void k_makew(const float* __restrict__ qA, const float* __restrict__ qB,
                        const float* __restrict__ kA, const float* __restrict__ kB,
                        const float* __restrict__ vA, const float* __restrict__ vB,
                        short* __restrict__ WT) {
  int g = blockIdx.x * 256 + threadIdx.x;
  int n4 = g % 576, kkb = g / 576;            // kkb in [0,192)
  int part = n4 / 192, nnb = (n4 % 192) * 4;
  const float* A = (part == 0) ? qA : (part == 1) ? kA : vA;
  const float* Bm = (part == 0) ? qB : (part == 1) ? kB : vB;
  float acc[4][4] = {};
  for (int r0 = 0; r0 < RANK; r0 += 4) {
    float4 a4[4], b4[4];
#pragma unroll
    for (int q = 0; q < 4; ++q)
      a4[q] = *(const float4*)&A[(kkb + q * 192) * RANK + r0];
#pragma unroll
    for (int i = 0; i < 4; ++i)
      b4[i] = *(const float4*)&Bm[(r0 + i) * 768 + nnb];
#pragma unroll
    for (int q = 0; q < 4; ++q) {
      const float* aq = (const float*)&a4[q];
#pragma unroll
      for (int i = 0; i < 4; ++i) {
        const float* bi = (const float*)&b4[i];
#pragma unroll
        for (int jn = 0; jn < 4; ++jn)
          acc[q][jn] += aq[i] * bi[jn];
      }
    }
  }
#pragma unroll
  for (int q = 0; q < 4; ++q)
#pragma unroll
    for (int jn = 0; jn < 4; ++jn)
      WT[(size_t)(part * 768 + nnb + jn) * 768 + kkb + q * 192] = f2bf(acc[q][jn]);
}

// ---------------- o_w transposed -> WT rows [2304,3072) ----------------
__global__ void k_wot(const float* __restrict__ ow, short* __restrict__ WT) {
  int g = blockIdx.x * 256 + threadIdx.x;     // 768*768 total
  int n = g % 768, kk = g / 768;
  WT[(size_t)(2304 + n) * 768 + kk] = f2bf(ow[(size_t)kk * 768 + n]);
}

// =====================================================================
// 256x256 8-phase GEMM (T2+T3+T4+T5), K=768, BK=64, 8 waves (2x4).
// XCD-chunked block mapping. MODE 0: fp32 out [row][ldc].
// MODE 2: bf16 out packed qkv — part p at Cv + p*PSTRIDE, [(b*6+h)][t][d].
// =====================================================================
__device__ inline s16x8 rdfrag(const short* hbase, int rowbyte, int ksl4x, int swz) {
  return *(const s16x8*)((const char*)hbase + rowbyte + (((ksl4x) ^ (swz)) << 4));
}

template <int MODE>
__global__ __launch_bounds__(512, 2) void k_gemm8(const short* __restrict__ A,
                                                  const short* __restrict__ Bt,
                                                  void* __restrict__ Cv, int ldc) {
  extern __shared__ short lds[];
  const int tid = threadIdx.x;
  const int wid = tid >> 6, lane = tid & 63;
  const int l15 = lane & 15, l4 = lane >> 4;
  const int wr = wid >> 2, wc = wid & 3;
  const int swz = l15 & 7;
  const int bid = blockIdx.y * 128 + blockIdx.x;
  const int nper = gridDim.y;
  const int xcd = bid & 7, loc = bid >> 3;
  const int mq = loc / nper;
  const int mt = xcd * 16 + mq;
  const int nt = loc - mq * nper;
  const long mbase = (long)mt * 256;
  const long nbase = (long)nt * 256;

  const int hb0 = wid * 2048 + lane * 16;
  const int hb1 = hb0 + 1024;
  const int r0 = hb0 >> 7, c0 = ((hb0 >> 4) & 7) ^ (r0 & 7);
  const int r1 = hb1 >> 7, c1 = ((hb1 >> 4) & 7) ^ (r1 & 7);
  const int off0 = r0 * 768 + c0 * 8;
  const int off1 = r1 * 768 + c1 * 8;

#define STAGE(G, rowoff, kt, ldsS) do {                                        \
    gload_lds16((G) + (size_t)(rowoff) * 768 + (kt) * 64 + off0,               \
                (char*)(ldsS) + wid * 2048);                                   \
    gload_lds16((G) + (size_t)(rowoff) * 768 + (kt) * 64 + off1,               \
                (char*)(ldsS) + wid * 2048 + 1024);                            \
  } while (0)

#define LDSA(buf, half) (lds + ((buf) * 2 + (half)) * 8192)
#define LDSB(buf, half) (lds + 32768 + ((buf) * 2 + (half)) * 8192)

  f32x4 acc[8][4] = {};

  STAGE(A,  mbase,       0, LDSA(0, 0));
  STAGE(Bt, nbase,       0, LDSB(0, 0));
  STAGE(A,  mbase + 128, 0, LDSA(0, 1));
  STAGE(Bt, nbase + 128, 0, LDSB(0, 1));
  STAGE(A,  mbase,       1, LDSA(1, 0));
  STAGE(Bt, nbase,       1, LDSB(1, 0));
  WAITVM4();
  BAR();

  s16x8 a03[4][2], a47[4][2], b01[2][2], b23[2][2];

#pragma unroll
  for (int kt = 0; kt < NK; ++kt) {
    const int buf = kt & 1, nbuf = buf ^ 1;
    const short* Ab = LDSA(buf, wr);
    const short* Bb = LDSB(buf, (wc >> 1));
    const int browbase = (wc & 1) * 64 * 128;

    // P0
#pragma unroll
    for (int mf = 0; mf < 4; ++mf)
#pragma unroll
      for (int ks = 0; ks < 2; ++ks)
        a03[mf][ks] = rdfrag(Ab, (mf * 16 + l15) * 128, ks * 4 + l4, swz);
#pragma unroll
    for (int nf = 0; nf < 2; ++nf)
#pragma unroll
      for (int ks = 0; ks < 2; ++ks)
        b01[nf][ks] = rdfrag(Bb, browbase + (nf * 16 + l15) * 128, ks * 4 + l4, swz);
    if (kt + 1 < NK) STAGE(A, mbase + 128, kt + 1, LDSA(nbuf, 1));
    BAR();
    LGKM0();
    __builtin_amdgcn_s_setprio(1);
#pragma unroll
    for (int mf = 0; mf < 4; ++mf)
#pragma unroll
      for (int nf = 0; nf < 2; ++nf)
#pragma unroll
        for (int ks = 0; ks < 2; ++ks)
          acc[mf][nf] = __builtin_amdgcn_mfma_f32_16x16x32_bf16(a03[mf][ks], b01[nf][ks], acc[mf][nf], 0, 0, 0);
    __builtin_amdgcn_s_setprio(0);
    BAR();

    // P1
#pragma unroll
    for (int mf = 0; mf < 4; ++mf)
#pragma unroll
      for (int ks = 0; ks < 2; ++ks)
        a47[mf][ks] = rdfrag(Ab, ((mf + 4) * 16 + l15) * 128, ks * 4 + l4, swz);
    if (kt + 1 < NK) STAGE(Bt, nbase + 128, kt + 1, LDSB(nbuf, 1));
    BAR();
    LGKM0();
    __builtin_amdgcn_s_setprio(1);
#pragma unroll
    for (int mf = 0; mf < 4; ++mf)
#pragma unroll
      for (int nf = 0; nf < 2; ++nf)
#pragma unroll
        for (int ks = 0; ks < 2; ++ks)
          acc[mf + 4][nf] = __builtin_amdgcn_mfma_f32_16x16x32_bf16(a47[mf][ks], b01[nf][ks], acc[mf + 4][nf], 0, 0, 0);
    __builtin_amdgcn_s_setprio(0);
    BAR();

    // P2
#pragma unroll
    for (int nf = 0; nf < 2; ++nf)
#pragma unroll
      for (int ks = 0; ks < 2; ++ks)
        b23[nf][ks] = rdfrag(Bb, browbase + ((nf + 2) * 16 + l15) * 128, ks * 4 + l4, swz);
    if (kt + 2 < NK) STAGE(A, mbase, kt + 2, LDSA(buf, 0));
    BAR();
    LGKM0();
    __builtin_amdgcn_s_setprio(1);
#pragma unroll
    for (int mf = 0; mf < 4; ++mf)
#pragma unroll
      for (int nf = 0; nf < 2; ++nf)
#pragma unroll
        for (int ks = 0; ks < 2; ++ks)
          acc[mf][nf + 2] = __builtin_amdgcn_mfma_f32_16x16x32_bf16(a03[mf][ks], b23[nf][ks], acc[mf][nf + 2], 0, 0, 0);
    __builtin_amdgcn_s_setprio(0);
    BAR();

    // P3
    if (kt + 2 < NK) STAGE(Bt, nbase, kt + 2, LDSB(buf, 0));
    BAR();
    __builtin_amdgcn_s_setprio(1);
#pragma unroll
    for (int mf = 0; mf < 4; ++mf)
#pragma unroll
      for (int nf = 0; nf < 2; ++nf)
#pragma unroll
        for (int ks = 0; ks < 2; ++ks)
          acc[mf + 4][nf + 2] = __builtin_amdgcn_mfma_f32_16x16x32_bf16(a47[mf][ks], b23[nf][ks], acc[mf + 4][nf + 2], 0, 0, 0);
    __builtin_amdgcn_s_setprio(0);
    if (kt < NK - 1) {
      if (kt + 2 < NK) WAITVM4(); else WAITVM0();
      BAR();
    }
  }
#undef STAGE

#pragma unroll
  for (int mf = 0; mf < 8; ++mf)
#pragma unroll
    for (int nf = 0; nf < 4; ++nf) {
      const int col = (int)(nbase + wc * 64 + nf * 16 + l15);
      const int part = col / 768;
      const int wi = col - part * 768;
      const int hh = wi >> 7, dd = wi & 127;
#pragma unroll
      for (int r = 0; r < 4; ++r) {
        long row = mbase + wr * 128 + mf * 16 + l4 * 4 + r;
        if (MODE == 0) {
          ((float*)Cv)[row * ldc + col] = acc[mf][nf][r];
        } else {
          // packed: part tensor, [(b*6+h)][t][d]
          size_t idx = (size_t)part * PSTRIDE +
                       (((size_t)(row >> 8) * 6 + hh) * 256 + (row & 255)) * 128 + dd;
          ((short*)Cv)[idx] = f2bf(acc[mf][nf][r]);
        }
      }
    }
}

// ---------------- RoPE on k only (packed layout, contiguous) ----------------
__global__ void k_ropek(short* __restrict__ kp, const float* __restrict__ cosT,
                        const float* __restrict__ sinT) {
  int tid = blockIdx.x * 256 + threadIdx.x;   // 768*256*8 total
  int bh = tid >> 11, rem = tid & 2047;
  int t = rem >> 3, i8 = (rem & 7) * 8;
  size_t base = ((size_t)bh * 256 + t) * 128 + i8;
  s16x8 a = *(const s16x8*)(kp + base);
  s16x8 b = *(const s16x8*)(kp + base + 64);
  const float4* cp = (const float4*)(cosT + t * 64 + i8);
  const float4* sp = (const float4*)(sinT + t * 64 + i8);
  float4 c04 = cp[0], c14 = cp[1], s04 = sp[0], s14 = sp[1];
  float cs[8] = {c04.x, c04.y, c04.z, c04.w, c14.x, c14.y, c14.z, c14.w};
  float sn[8] = {s04.x, s04.y, s04.z, s04.w, s14.x, s14.y, s14.z, s14.w};
  s16x8 na, nb;
#pragma unroll
  for (int j = 0; j < 8; ++j) {
    float av = bf2f(a[j]), bv = bf2f(b[j]);
    na[j] = f2bf(av * cs[j] - bv * sn[j]);
    nb[j] = f2bf(bv * cs[j] + av * sn[j]);
  }
  *(s16x8*)(kp + base) = na;
  *(s16x8*)(kp + base + 64) = nb;
}

// ---------------- flash attention (R4 structure, packed q/k/v) ----------------
// LDS (dynamic 80KB): Kls[2][64*128] | Vt[128*64] | Pls[8][32*64], XOR-swizzled.
// Softmax reductions via DPP row_ror (VALU) instead of ds_swizzle (LDS pipe).
__global__ __launch_bounds__(512) void k_attn(const short* __restrict__ qp,
                                              const short* __restrict__ kp,
                                              const short* __restrict__ vp,
                                              short* __restrict__ attout,
                                              const float* __restrict__ cosT,
                                              const float* __restrict__ sinT) {
  extern __shared__ short smem[];
  short* Kls0 = smem;
  short* Kls1 = smem + 8192;
  short* Vt   = smem + 16384;
  const int tid = threadIdx.x;
  const int wid = tid >> 6, lane = tid & 63;
  const int l15 = lane & 15, l4 = lane >> 4;
  short* PlsW = smem + 24576 + wid * 2048;
  const int bh = blockIdx.x;                // b*N_HEADS + h
  const int b = bh / N_HEADS, h = bh % N_HEADS;
  const long row0 = (long)b * TT;
  const size_t pbase = (size_t)bh * 256 * 128;
  const int d0 = wid * 16;

  // --- load raw Q fragments, rope + scale in-register ---
  s16x8 qf[2][4];
#pragma unroll
  for (int mi = 0; mi < 2; ++mi)
#pragma unroll
    for (int kc = 0; kc < 4; ++kc) {
      int t = wid * 32 + mi * 16 + l15;
      qf[mi][kc] = *(const s16x8*)(qp + pbase + (size_t)t * 128 + kc * 32 + l4 * 8);
    }
#pragma unroll
  for (int mi = 0; mi < 2; ++mi) {
    int t = wid * 32 + mi * 16 + l15;
#pragma unroll
    for (int kc = 0; kc < 2; ++kc) {
      const float4* cp = (const float4*)(cosT + t * 64 + kc * 32 + l4 * 8);
      const float4* sp = (const float4*)(sinT + t * 64 + kc * 32 + l4 * 8);
      float4 c04 = cp[0], c14 = cp[1], s04 = sp[0], s14 = sp[1];
      float cs[8] = {c04.x, c04.y, c04.z, c04.w, c14.x, c14.y, c14.z, c14.w};
      float sn[8] = {s04.x, s04.y, s04.z, s04.w, s14.x, s14.y, s14.z, s14.w};
#pragma unroll
      for (int jj = 0; jj < 8; ++jj) {
        float av = bf2f(qf[mi][kc][jj]);
        float bv = bf2f(qf[mi][kc + 2][jj]);
        qf[mi][kc][jj]     = f2bf((av * cs[jj] - bv * sn[jj]) * QSCL);
        qf[mi][kc + 2][jj] = f2bf((bv * cs[jj] + av * sn[jj]) * QSCL);
      }
    }
  }

#define STAGEK(j_, Kd) do {                                                     \
    int bb0_ = wid * 2048 + lane * 16;                                          \
    int r0_ = bb0_ >> 8; int sc0_ = ((bb0_ >> 4) & 15) ^ (r0_ & 7);             \
    gload_lds16(kp + pbase + (size_t)((j_) * 64 + r0_) * 128 + sc0_ * 8,        \
                (char*)(Kd) + wid * 2048);                                      \
    int bb1_ = bb0_ + 1024;                                                     \
    int r1_ = bb1_ >> 8; int sc1_ = ((bb1_ >> 4) & 15) ^ (r1_ & 7);             \
    gload_lds16(kp + pbase + (size_t)((j_) * 64 + r1_) * 128 + sc1_ * 8,        \
                (char*)(Kd) + wid * 2048 + 1024);                               \
  } while (0)

#define LOADV(j_, va, vb) do {                                                  \
    const short* vsrc_ = vp + pbase + (size_t)((j_) * 64 + lane) * 128 + d0;    \
    va = *(const s16x8*)vsrc_;                                                  \
    vb = *(const s16x8*)(vsrc_ + 8);                                            \
  } while (0)

  float mst[2][4], lst[2][4];
  f32x4 oacc[2][8];
#pragma unroll
  for (int mi = 0; mi < 2; ++mi)
#pragma unroll
    for (int r = 0; r < 4; ++r) { mst[mi][r] = -1e30f; lst[mi][r] = 0.f; }
#pragma unroll
  for (int mi = 0; mi < 2; ++mi)
#pragma unroll
    for (int nd = 0; nd < 8; ++nd) oacc[mi][nd] = {0.f, 0.f, 0.f, 0.f};

  const int jmax = (wid * 32 + 31) / 64;

  // prologue: stage tile 0
  STAGEK(0, Kls0);
  s16x8 vr[2][2];
  LOADV(0, vr[0][0], vr[0][1]);

#pragma unroll
  for (int j = 0; j < 4; ++j) {
    const int buf = j & 1;
    const short* Kb = buf ? Kls1 : Kls0;
    short* Kn = buf ? Kls0 : Kls1;
    // prefetch next tile (K -> LDS, V -> regs)
    if (j < 3) {
      STAGEK(j + 1, Kn);
      LOADV(j + 1, vr[buf ^ 1][0], vr[buf ^ 1][1]);
    }
    if (j < 3) WAITVM4(); else WAITVM0();
    __builtin_amdgcn_sched_barrier(0);
    BAR();
    // --- transpose-write V(j) into swizzled Vt ---
#pragma unroll
    for (int e = 0; e < 8; ++e)
      *(short*)((char*)Vt + (d0 + e) * 128 + (((lane >> 3) ^ e) << 4) + (lane & 7) * 2) = vr[buf][0][e];
#pragma unroll
    for (int e = 0; e < 8; ++e)
      *(short*)((char*)Vt + (d0 + 8 + e) * 128 + (((lane >> 3) ^ e) << 4) + (lane & 7) * 2) = vr[buf][1][e];

    if (j <= jmax) {
      // --- S = Q K^T ---
      f32x4 sacc[2][4] = {};
#pragma unroll
      for (int kc = 0; kc < 4; ++kc) {
        s16x8 kf[4];
#pragma unroll
        for (int ni = 0; ni < 4; ++ni)
          kf[ni] = *(const s16x8*)((const char*)Kb + (ni * 16 + l15) * 256 +
                                   (((kc * 4 + l4) ^ (l15 & 7)) << 4));
#pragma unroll
        for (int mi = 0; mi < 2; ++mi)
#pragma unroll
          for (int ni = 0; ni < 4; ++ni)
            sacc[mi][ni] = __builtin_amdgcn_mfma_f32_16x16x32_bf16(qf[mi][kc], kf[ni], sacc[mi][ni], 0, 0, 0);
      }
      // --- causal mask + online softmax (DPP reductions) ---
#pragma unroll
      for (int mi = 0; mi < 2; ++mi) {
#pragma unroll
        for (int r = 0; r < 4; ++r) {
          int qr = wid * 32 + mi * 16 + l4 * 4 + r;
          float rm = -1e30f;
#pragma unroll
          for (int ni = 0; ni < 4; ++ni) {
            int kvc = j * 64 + ni * 16 + l15;
            if (kvc > qr) sacc[mi][ni][r] = -1e30f;
            rm = fmaxf(rm, sacc[mi][ni][r]);
          }
          rm = red16_max(rm);
          float mold = mst[mi][r];
          float mnew = fmaxf(mold, rm);
          float alpha = __expf(mold - mnew);
          mst[mi][r] = mnew;
          float rs = 0.f;
#pragma unroll
          for (int ni = 0; ni < 4; ++ni) {
            float p = __expf(sacc[mi][ni][r] - mnew);
            sacc[mi][ni][r] = p;
            rs += p;
          }
          rs = red16_sum(rs);
          lst[mi][r] = lst[mi][r] * alpha + rs;
#pragma unroll
          for (int nd = 0; nd < 8; ++nd)
            oacc[mi][nd][r] *= alpha;
        }
      }
      // --- P -> bf16 into swizzled per-wave Pls ---
#pragma unroll
      for (int mi = 0; mi < 2; ++mi)
#pragma unroll
        for (int ni = 0; ni < 4; ++ni)
#pragma unroll
          for (int r = 0; r < 4; ++r) {
            int prow = mi * 16 + l4 * 4 + r;
            int pcp = (ni * 2 + (l15 >> 3)) ^ (prow & 7);
            *(short*)((char*)PlsW + prow * 128 + (pcp << 4) + (l15 & 7) * 2) =
                f2bf(sacc[mi][ni][r]);
          }
    }
    LGKM0();
    BAR();
    __builtin_amdgcn_sched_barrier(0);
    if (j <= jmax) {
      // --- O += P V ---
#pragma unroll
      for (int kc2 = 0; kc2 < 2; ++kc2) {
        s16x8 pa[2];
#pragma unroll
        for (int mi = 0; mi < 2; ++mi)
          pa[mi] = *(const s16x8*)((const char*)PlsW + (mi * 16 + l15) * 128 +
                                   (((kc2 * 4 + l4) ^ (l15 & 7)) << 4));
#pragma unroll
        for (int nd = 0; nd < 8; ++nd) {
          s16x8 vf = *(const s16x8*)((const char*)Vt + (nd * 16 + l15) * 128 +
                                     (((kc2 * 4 + l4) ^ (l15 & 7)) << 4));
#pragma unroll
          for (int mi = 0; mi < 2; ++mi)
            oacc[mi][nd] = __builtin_amdgcn_mfma_f32_16x16x32_bf16(pa[mi], vf, oacc[mi][nd], 0, 0, 0);
        }
      }
    }
  }
#undef STAGEK
#undef LOADV
#pragma unroll
  for (int mi = 0; mi < 2; ++mi)
#pragma unroll
    for (int nd = 0; nd < 8; ++nd)
#pragma unroll
      for (int r = 0; r < 4; ++r) {
        long row = row0 + wid * 32 + mi * 16 + l4 * 4 + r;
        int col = h * HD + nd * 16 + l15;
        attout[row * D_MODEL + col] = f2bf(oacc[mi][nd][r] / lst[mi][r]);
      }
}

extern "C" void kernel_launch(void* const* d_in, const int* in_sizes, int n_in,
                              void* d_out, int out_size, void* d_ws, size_t ws_size,
                              hipStream_t stream) {
  const float* x  = (const float*)d_in[0];
  const float* qA = (const float*)d_in[1];
  const float* qB = (const float*)d_in[2];
  const float* kA = (const float*)d_in[3];
  const float* kB = (const float*)d_in[4];
  const float* vA = (const float*)d_in[5];
  const float* vB = (const float*)d_in[6];
  const float* ow = (const float*)d_in[7];

  char* ws = (char*)d_ws;
  short* qkvp  = (short*)ws;                          // 3 packed tensors, 48MB each
  short* qp    = qkvp;
  short* kp    = qkvp + (size_t)PSTRIDE;
  short* vp    = qkvp + (size_t)2 * PSTRIDE;
  short* xb    = (short*)(ws + 150994944);            // [32768][768] bf16, reused as attout
  short* WT    = (short*)(ws + 201326592);            // [3072][768]  bf16
  float* cosT  = (float*)(ws + 206045184);            // [256][64] fp32
  float* sinT  = (float*)(ws + 206110720);            // [256][64] fp32
  short* attout = xb;

  hipFuncSetAttribute((const void*)k_gemm8<2>,
                      hipFuncAttributeMaxDynamicSharedMemorySize, 131072);
  hipFuncSetAttribute((const void*)k_gemm8<0>,
                      hipFuncAttributeMaxDynamicSharedMemorySize, 131072);
  hipFuncSetAttribute((const void*)k_attn,
                      hipFuncAttributeMaxDynamicSharedMemorySize, 81920);

  k_tables<<<64, 256, 0, stream>>>(cosT, sinT);
  k_castx<<<12288, 256, 0, stream>>>(x, xb);
  k_makew<<<432, 256, 0, stream>>>(qA, qB, kA, kB, vA, vB, WT);
  k_wot<<<2304, 256, 0, stream>>>(ow, WT);
  // qkv = xb @ [Wq|Wk|Wv], written packed [(b*6+h)][t][d] per part
  k_gemm8<2><<<dim3(128, 9), 512, 131072, stream>>>(xb, WT, (void*)qkvp, 0);
  // rope k in place (packed, contiguous)
  k_ropek<<<6144, 256, 0, stream>>>(kp, cosT, sinT);
  // attention -> attout (aliases xb)
  k_attn<<<768, 512, 81920, stream>>>(qp, kp, vp, attout, cosT, sinT);
  // final projection -> d_out fp32  (M=32768, N=768, K=768)
  k_gemm8<0><<<dim3(128, 3), 512, 131072, stream>>>(attout, WT + (size_t)2304 * 768, d_out, 768);
}